// Round 6
// baseline (406.094 us; speedup 1.0000x reference)
//
#include <hip/hip_runtime.h>
#include <math.h>

// Problem constants
#define TT 32
#define BB 128
#define DD 256
#define HH 768
#define MAXP 8

// 8 rowgroups (16 rows) x 12 col-blocks (64 cols); 256 thr = 4 waves = 4 col-tiles
#define RG   8
#define RPG  16
#define CB   12
#define CS   64
#define NTH  256
#define NCH  24    // K chunks of 32

#define OFF_LAST  ((size_t)TT * BB * HH)
#define OFF_PCOST (OFF_LAST + (size_t)BB * HH)
#define OFF_STEPS (OFF_PCOST + BB)

#define ASCOPE __HIP_MEMORY_SCOPE_AGENT

typedef __attribute__((ext_vector_type(8))) short s16x8;
typedef __attribute__((ext_vector_type(4))) float f32x4;
typedef unsigned long long ull;

static __device__ __forceinline__ unsigned short f2bf(float f) {
    unsigned u = __float_as_uint(f);
    u = (u + 0x7fffu + ((u >> 16) & 1u)) >> 16;   // RNE
    return (unsigned short)u;
}
static __device__ __forceinline__ float bf2f(unsigned short h) {
    return __uint_as_float(((unsigned)h) << 16);
}

__launch_bounds__(NTH, 1)
__global__ void act_kernel(const float* __restrict__ x,
                           const float* __restrict__ Wih,
                           const float* __restrict__ Whh,
                           const float* __restrict__ bih,
                           const float* __restrict__ bhh,
                           const float* __restrict__ wpv,
                           const float* __restrict__ bp,
                           float* __restrict__ out,
                           unsigned* __restrict__ flags,
                           ull* __restrict__ hxe)
{
    const int tid  = threadIdx.x;
    const int g    = blockIdx.x & 7;     // rowgroup (XCD swizzle: perf heuristic only)
    const int ib   = blockIdx.x >> 3;    // col-block [0,12)
    const int r0   = g * RPG;
    const int c0   = ib * CS;
    const int CT   = tid >> 6;           // wave = col-tile [0,4)
    const int lane = tid & 63;
    const int am   = lane & 15;          // this thread's batch row (A-row / C-col)
    const int aq   = lane >> 4;

    // LDS ~69 KB -> 1 block/CU
    __shared__ s16x8 A_s[NCH * 64];          // hx A-frags (24.5 KB)
    __shared__ s16x8 WB_s[4 * 8 * 64];       // Wih B-frags (32 KB)
    __shared__ s16x8 xA_s[8 * 64];           // x_t A-frags (8 KB)
    __shared__ unsigned short hxn_s[RPG][72];
    __shared__ float zw_s[4][20];
    __shared__ float bias_s[CS], wflag_s[CS];

    // ---- init: Whh B-frags -> permanent VGPRs (96) ----
    s16x8 Breg[NCH];
    {
        const float* wr = Whh + (size_t)(c0 + CT*16 + am) * HH + aq*8;
        for (int ch = 0; ch < NCH; ++ch) {
            float4 a0 = *(const float4*)(wr + ch*32);
            float4 a1 = *(const float4*)(wr + ch*32 + 4);
            union { s16x8 v; unsigned short e[8]; } u;
            u.e[0]=f2bf(a0.x); u.e[1]=f2bf(a0.y); u.e[2]=f2bf(a0.z); u.e[3]=f2bf(a0.w);
            u.e[4]=f2bf(a1.x); u.e[5]=f2bf(a1.y); u.e[6]=f2bf(a1.z); u.e[7]=f2bf(a1.w);
            Breg[ch] = u.v;
        }
    }
    for (int ch = 0; ch < 8; ++ch) {   // Wih B-frags (row stride 257 -> scalar, init-only)
        const float* wr = Wih + (size_t)(c0 + CT*16 + am) * (DD+1) + ch*32 + aq*8;
        union { s16x8 v; unsigned short e[8]; } u;
        #pragma unroll
        for (int j = 0; j < 8; ++j) u.e[j] = f2bf(wr[j]);
        WB_s[(CT*8 + ch)*64 + lane] = u.v;
    }
    if (tid < CS) {
        bias_s[tid]  = bih[c0+tid] + bhh[c0+tid];
        wflag_s[tid] = Wih[(size_t)(c0+tid)*(DD+1) + DD];
    }
    const float bpr = bp[0];
    float wpreg[48];                    // w_p for this thread's 48 columns
    #pragma unroll
    for (int j = 0; j < 6; ++j)
        #pragma unroll
        for (int i = 0; i < 8; ++i)
            wpreg[j*8+i] = wpv[(j*4 + CT)*32 + aq*8 + i];
    {
        s16x8 z8 = {0,0,0,0,0,0,0,0};
        #pragma unroll
        for (int j = 0; j < 6; ++j) A_s[j*NTH + tid] = z8;   // hx0 = 0
    }

    float ahx[48];
    unsigned it = 0;   // monotone phase counter (phase k stores k+1; flags memset to 0)
    // per-thread replicated ponder state for row am (bitwise-identical everywhere)
    float ahR = 0.f, spcR = 0.f, scR = 0.f, pcR = 0.f;
    int   actR = 1;

    // prefetch x(0)
    float4 xp0, xp1, xp2, xp3;
    {
        const float* xb = x + (size_t)(r0 + am)*DD;
        xp0 = *(const float4*)(xb + CT*32 + aq*8);
        xp1 = *(const float4*)(xb + CT*32 + aq*8 + 4);
        xp2 = *(const float4*)(xb + (4+CT)*32 + aq*8);
        xp3 = *(const float4*)(xb + (4+CT)*32 + aq*8 + 4);
    }
    __syncthreads();   // WB_s / bias_s ready

    for (int t = 0; t < TT; ++t) {
        // ---- pack prefetched x_t into A-frags ----
        {
            union { s16x8 v; unsigned short e[8]; } u;
            u.e[0]=f2bf(xp0.x); u.e[1]=f2bf(xp0.y); u.e[2]=f2bf(xp0.z); u.e[3]=f2bf(xp0.w);
            u.e[4]=f2bf(xp1.x); u.e[5]=f2bf(xp1.y); u.e[6]=f2bf(xp1.z); u.e[7]=f2bf(xp1.w);
            xA_s[tid] = u.v;
            u.e[0]=f2bf(xp2.x); u.e[1]=f2bf(xp2.y); u.e[2]=f2bf(xp2.z); u.e[3]=f2bf(xp2.w);
            u.e[4]=f2bf(xp3.x); u.e[5]=f2bf(xp3.y); u.e[6]=f2bf(xp3.z); u.e[7]=f2bf(xp3.w);
            xA_s[NTH + tid] = u.v;
        }
        ahR = 0.f; spcR = 0.f; scR = 0.f; actR = 1;
        #pragma unroll
        for (int q = 0; q < 48; ++q) ahx[q] = 0.f;
        __syncthreads();

        // ---- xi = x_t @ Wih^T + bias (2 independent MFMA chains) ----
        f32x4 xi;
        {
            f32x4 a0 = {0.f,0.f,0.f,0.f}, a1 = {0.f,0.f,0.f,0.f};
            #pragma unroll
            for (int ch = 0; ch < 8; ch += 2) {
                a0 = __builtin_amdgcn_mfma_f32_16x16x32_bf16(
                        xA_s[ch*64 + lane],     WB_s[(CT*8 + ch)*64 + lane],     a0, 0,0,0);
                a1 = __builtin_amdgcn_mfma_f32_16x16x32_bf16(
                        xA_s[(ch+1)*64 + lane], WB_s[(CT*8 + ch+1)*64 + lane],   a1, 0,0,0);
            }
            const float bs = bias_s[CT*16 + am];
            xi[0]=a0[0]+a1[0]+bs; xi[1]=a0[1]+a1[1]+bs;
            xi[2]=a0[2]+a1[2]+bs; xi[3]=a0[3]+a1[3]+bs;
        }
        // prefetch x(t+1) (in flight across the ponder loop)
        if (t + 1 < TT) {
            const float* xb = x + ((size_t)(t+1)*BB + r0 + am)*DD;
            xp0 = *(const float4*)(xb + CT*32 + aq*8);
            xp1 = *(const float4*)(xb + CT*32 + aq*8 + 4);
            xp2 = *(const float4*)(xb + (4+CT)*32 + aq*8);
            xp3 = *(const float4*)(xb + (4+CT)*32 + aq*8 + 4);
        }

        // ---- ponder loop ----
        int pk = 0;
        for (;;) {
            const unsigned par = it & 1u;
            ull* exch = hxe + (size_t)(g*2 + par) * (NCH*64*2);

            // matvec: 2 independent MFMA chains over K
            f32x4 a0 = xi, a1 = {0.f,0.f,0.f,0.f};
            #pragma unroll
            for (int ch = 0; ch < NCH; ch += 2) {
                a0 = __builtin_amdgcn_mfma_f32_16x16x32_bf16(A_s[ch*64 + lane],     Breg[ch],   a0, 0,0,0);
                a1 = __builtin_amdgcn_mfma_f32_16x16x32_bf16(A_s[(ch+1)*64 + lane], Breg[ch+1], a1, 0,0,0);
            }
            const float fl = pk ? wflag_s[CT*16 + am] : 0.f;
            #pragma unroll
            for (int r = 0; r < 4; ++r)
                hxn_s[aq*4 + r][CT*16 + am] = f2bf(tanhf(a0[r] + a1[r] + fl));
            __syncthreads();   // S1: hxn_s ready

            // publish own 64-col slice in A-frag layout (256 lanes, 1 ull each)
            {
                const int u4  = tid >> 6, l = tid & 63;
                const int chd = u4 >> 1, half = u4 & 1;
                const int pm  = l & 15, pq = l >> 4;
                const ull v = *(const ull*)&hxn_s[pm][chd*32 + pq*8 + half*4];
                __hip_atomic_store(exch + ((size_t)((2*ib + chd)*64 + l)*2 + half),
                                   v, __ATOMIC_RELAXED, ASCOPE);
            }
            ++it;
            __syncthreads();   // S2: all publish stores drained (compiler vmcnt before barrier)
            if (tid == 0)
                __hip_atomic_store(&flags[g*16 + ib], it, __ATOMIC_RELEASE, ASCOPE);
            if (tid < 64) {
                const unsigned* fa = &flags[g*16 + (tid % 12)];
                unsigned v;
                do { v = __hip_atomic_load(fa, __ATOMIC_RELAXED, ASCOPE); }
                while (!__all((int)(v >= it)));
                __builtin_amdgcn_fence(__ATOMIC_ACQUIRE, "agent");
            }
            __syncthreads();   // S3: barrier passed

            // fan-in: full 16x768 new hx (A-frag layout), 12 ull/thread
            ull nlo[6], nhi[6];
            #pragma unroll
            for (int j = 0; j < 6; ++j) {
                ull* src = exch + (size_t)(j*NTH + tid)*2;
                nlo[j] = __hip_atomic_load(src,     __ATOMIC_RELAXED, ASCOPE);
                nhi[j] = __hip_atomic_load(src + 1, __ATOMIC_RELAXED, ASCOPE);
            }

            // z for row am: per-thread partial (fixed order) -> butterfly -> cross-wave
            float zp = 0.f;
            #pragma unroll
            for (int j = 0; j < 6; ++j) {
                const ull lo = nlo[j], hi = nhi[j];
                #pragma unroll
                for (int i = 0; i < 4; ++i) {
                    zp += bf2f((unsigned short)(lo >> (16*i))) * wpreg[j*8 + i];
                    zp += bf2f((unsigned short)(hi >> (16*i))) * wpreg[j*8 + 4 + i];
                }
            }
            zp += __shfl_xor(zp, 16);
            zp += __shfl_xor(zp, 32);
            if (lane < 16) zw_s[CT][lane] = zp;
            __syncthreads();   // S4: zw ready
            const float z = ((zw_s[0][am] + zw_s[1][am]) + zw_s[2][am]) + zw_s[3][am];

            // replicated scalar ponder update (row am; identical in every thread/block)
            float w1 = 0.f;
            if (actR) {
                const float h = 1.f / (1.f + expf(-(z + bpr)));
                spcR = -ahR;
                const float ah2 = ahR + h;
                const float p = h - fmaxf(ah2 - 1.f, 0.f);
                w1 = 1.f + p;
                scR += 1.f;
                ahR = ah2;
                actR = (ah2 < 0.99f) ? 1 : 0;   // 1-EPS == 0.99f exactly
            }

            // accum_hx + hx_i freeze (w1!=0 <=> row active this iteration)
            if (w1 != 0.f) {
                #pragma unroll
                for (int j = 0; j < 6; ++j) {
                    const ull lo = nlo[j], hi = nhi[j];
                    #pragma unroll
                    for (int i = 0; i < 4; ++i) {
                        ahx[j*8 + i]     += w1 * bf2f((unsigned short)(lo >> (16*i)));
                        ahx[j*8 + 4 + i] += w1 * bf2f((unsigned short)(hi >> (16*i)));
                    }
                    union { ull u[2]; s16x8 v; } cv; cv.u[0] = lo; cv.u[1] = hi;
                    A_s[j*NTH + tid] = cv.v;
                }
            }
            const int nact = (int)__popcll(__ballot(actR != 0) & 0xFFFFull);
            ++pk;
            __syncthreads();   // S5: A_s ready for next matvec
            if (nact == 0 || pk == MAXP) break;
        }

        // ---- finalize t (state replicated -> no extra sync) ----
        pcR += spcR;
        const float inv = 1.f / scR;
        if (ib == 0 && tid < 16) out[OFF_STEPS + (size_t)t*BB + r0 + tid] = scR;
        #pragma unroll
        for (int j = 0; j < 6; ++j) {
            float o[8];
            #pragma unroll
            for (int i = 0; i < 8; ++i) o[i] = ahx[j*8 + i] * inv;
            union { s16x8 v; unsigned short e[8]; } u;
            #pragma unroll
            for (int i = 0; i < 8; ++i) u.e[i] = f2bf(o[i]);
            A_s[j*NTH + tid] = u.v;   // hx for next t (replicated in every block)
            if (ib == 0) {
                float* op = out + ((size_t)t*BB + r0 + am)*HH + (j*4 + CT)*32 + aq*8;
                *(float4*)op       = make_float4(o[0], o[1], o[2], o[3]);
                *(float4*)(op + 4) = make_float4(o[4], o[5], o[6], o[7]);
                if (t == TT-1) {
                    float* lp = out + OFF_LAST + (size_t)(r0 + am)*HH + (j*4 + CT)*32 + aq*8;
                    *(float4*)lp       = make_float4(o[0], o[1], o[2], o[3]);
                    *(float4*)(lp + 4) = make_float4(o[4], o[5], o[6], o[7]);
                }
            }
        }
        __syncthreads();
    }
    if (ib == 0 && tid < 16) out[OFF_PCOST + r0 + tid] = pcR;
}

extern "C" void kernel_launch(void* const* d_in, const int* in_sizes, int n_in,
                              void* d_out, int out_size, void* d_ws, size_t ws_size,
                              hipStream_t stream) {
    const float* x   = (const float*)d_in[0];
    const float* Wih = (const float*)d_in[1];
    const float* Whh = (const float*)d_in[2];
    const float* bih = (const float*)d_in[3];
    const float* bhh = (const float*)d_in[4];
    const float* wpv = (const float*)d_in[5];
    const float* bp  = (const float*)d_in[6];
    float* out = (float*)d_out;

    // ws: [0,4096) phase flags (memset-zeroed every call);
    // then hx exchange (bf16 A-frag layout, double-parity per rowgroup: 384 KB)
    unsigned* flags = (unsigned*)d_ws;
    ull*      hxe   = (ull*)((char*)d_ws + 4096);

    hipMemsetAsync(d_ws, 0, 4096, stream);
    act_kernel<<<dim3(RG*CB), dim3(NTH), 0, stream>>>(
        x, Wih, Whh, bih, bhh, wpv, bp, out, flags, hxe);
}